// Round 12
// baseline (1110.644 us; speedup 1.0000x reference)
//
#include <hip/hip_runtime.h>
#include <stdint.h>

typedef __bf16 bf16x8 __attribute__((ext_vector_type(8)));
typedef float f32x4 __attribute__((ext_vector_type(4)));

__device__ __forceinline__ uint32_t f2bf(float f) {
  uint32_t u = __builtin_bit_cast(uint32_t, f);
  return (u + 0x7fffu + ((u >> 16) & 1u)) >> 16;
}

__device__ __forceinline__ void gld_lds16(const void* g, void* l) {
  __builtin_amdgcn_global_load_lds(
      (const __attribute__((address_space(1))) void*)g,
      (__attribute__((address_space(3))) void*)l, 16, 0, 0);
}

// ---- fused weight prep: all 5 transposes + zp zeroing in one launch.
__global__ __launch_bounds__(256) void wprep_all_kernel(
    const float* __restrict__ Wd0, const float* __restrict__ W1,
    const float* __restrict__ Wd1, const float* __restrict__ W2,
    const float* __restrict__ Wd2,
    uint16_t* __restrict__ Td0, uint16_t* __restrict__ T1,
    uint16_t* __restrict__ Td1, uint16_t* __restrict__ T2,
    uint16_t* __restrict__ Td2, uint16_t* __restrict__ zp) {
  int i = blockIdx.x * 256 + threadIdx.x;
  if (i < 256) zp[i] = 0;
  constexpr int S0 = 27 * 64 * 128;
  constexpr int S1 = 27 * 128 * 128;
  if (i < S0) {
    int k = i >> 13, r = i & 8191;
    int co = r >> 6, ci = r & 63;
    Td0[i] = (uint16_t)f2bf(Wd0[(k * 64 + ci) * 128 + co]);
    return;
  }
  i -= S0;
  const float* src;
  uint16_t* dst;
  if (i < S1)          { src = W1;  dst = T1; }
  else if (i < 2 * S1) { src = Wd1; dst = Td1; i -= S1; }
  else if (i < 3 * S1) { src = W2;  dst = T2;  i -= 2 * S1; }
  else if (i < 4 * S1) { src = Wd2; dst = Td2; i -= 3 * S1; }
  else return;
  int k = i >> 14, r = i & 16383;
  int co = r >> 7, ci = r & 127;
  dst[i] = (uint16_t)f2bf(src[(k * 128 + ci) * 128 + co]);
}

// ---- conv0: Cin=3 -> Cout=64, fp32 in, bf16 out. Point-per-thread.
__global__ __launch_bounds__(256) void conv0_kernel(
    const float* __restrict__ x, const int* __restrict__ km,
    const float* __restrict__ W0, const float* __restrict__ b0,
    uint16_t* __restrict__ h0, int N) {
  __shared__ float Ws[27 * 192 + 64];
  for (int i = threadIdx.x; i < 27 * 192; i += 256) Ws[i] = W0[i];
  if (threadIdx.x < 64) Ws[27 * 192 + threadIdx.x] = b0[threadIdx.x];
  __syncthreads();
  const int n = blockIdx.x * 256 + threadIdx.x;
  if (n >= N) return;

  int idx[27];
  #pragma unroll
  for (int k = 0; k < 27; ++k) idx[k] = km[(size_t)k * N + n];

  f32x4 acc[16];
  #pragma unroll
  for (int c = 0; c < 16; ++c) acc[c] = *(const f32x4*)&Ws[27 * 192 + c * 4];

  #pragma unroll
  for (int k = 0; k < 27; ++k) {
    if (idx[k] >= 0) {
      const float* xr = x + (size_t)idx[k] * 3;
      const float x0 = xr[0], x1 = xr[1], x2 = xr[2];
      const float* wk = Ws + k * 192;
      #pragma unroll
      for (int c = 0; c < 16; ++c) {
        const f32x4 w0 = *(const f32x4*)(wk + c * 4);
        const f32x4 w1 = *(const f32x4*)(wk + 64 + c * 4);
        const f32x4 w2 = *(const f32x4*)(wk + 128 + c * 4);
        acc[c] += x0 * w0 + x1 * w1 + x2 * w2;
      }
    }
  }

  uint16_t* out = h0 + (size_t)n * 64;
  #pragma unroll
  for (int g = 0; g < 8; ++g) {
    int4 v;
    v.x = (int)(f2bf(acc[g * 2][0]) | (f2bf(acc[g * 2][1]) << 16));
    v.y = (int)(f2bf(acc[g * 2][2]) | (f2bf(acc[g * 2][3]) << 16));
    v.z = (int)(f2bf(acc[g * 2 + 1][0]) | (f2bf(acc[g * 2 + 1][1]) << 16));
    v.w = (int)(f2bf(acc[g * 2 + 1][2]) | (f2bf(acc[g * 2 + 1][3]) << 16));
    *(int4*)(out + g * 8) = v;
  }
}

// =====================================================================
// CHAMPION (r5 structure) + r12 sparsity masks: per-(tap, 16-row-group)
// validity; dead groups skip A-stage, a-ds_read, and MFMAs (exact: they
// contribute zero). Wave-uniform branches; barriers unconditional.
// =====================================================================
template <int CIN, bool OUTF32, bool RELU, bool SHADOW>
__global__ __launch_bounds__(512, 4) void sconv_pipe2_kernel(
    const uint16_t* __restrict__ fin, const int* __restrict__ kmap,
    const uint16_t* __restrict__ Wt, const float* __restrict__ bias,
    float* __restrict__ outf, uint16_t* __restrict__ outb,
    const uint16_t* __restrict__ zp, int Nout) {
  constexpr int QH = CIN / 32;   // 32-col quarters per row
  constexpr int S = 27 * QH;
  __shared__ __align__(16) uint16_t As[2][256 * 32];
  __shared__ __align__(16) uint16_t Bs[2][128 * 32];
  __shared__ int idxs[27 * 256];
  __shared__ unsigned char msk[27 * 16];   // [tap][16-row group] any-valid

  const int t = threadIdx.x;
  const int lane = t & 63, w = t >> 6;
  const int wr = w >> 1, wc = w & 1;

  // bijective XCD-chunked swizzle (m204)
  const int nwg = gridDim.x;
  int bid = blockIdx.x;
  if (nwg >= 8) {
    const int q = nwg >> 3, r = nwg & 7;
    const int xcd = bid & 7, pos = bid >> 3;
    bid = (xcd < r ? xcd * (q + 1) : r * (q + 1) + (xcd - r) * q) + pos;
  }
  const int n0 = bid * 256;

  for (int i = t; i < 27 * 256; i += 512) {
    int n = n0 + (i & 255);
    idxs[i] = (n < Nout) ? kmap[(size_t)(i >> 8) * Nout + n] : -1;
  }
  __syncthreads();

  // build group-validity masks (432 entries, <=1 per thread)
  if (t < 27 * 16) {
    const int* ip = &idxs[(t >> 4) * 256 + (t & 15) * 16];
    int any = 0;
    #pragma unroll
    for (int j = 0; j < 16; ++j) any |= (ip[j] >= 0) ? 1 : 0;
    msk[t] = (unsigned char)any;
  }
  __syncthreads();

  f32x4 acc[4][4] = {};

  auto stage = [&](int ss, int nb) {
    const int k = ss / QH;
    const int q = ss & (QH - 1);
    // A: 2 x 16B chunks per thread; group = w + j*8; skip dead groups
    #pragma unroll
    for (int j = 0; j < 2; ++j) {
      if (msk[k * 16 + w + j * 8]) {
        const int base = w * 64 + j * 512;
        const int row = (base >> 2) + (lane >> 2);
        const int sw = (lane & 3) ^ ((row >> 1) & 3);
        const int idx = idxs[k * 256 + row];
        const void* srcA = (idx >= 0)
            ? (const void*)(fin + (size_t)idx * CIN + q * 32 + sw * 8)
            : (const void*)zp;
        gld_lds16(srcA, (char*)&As[nb][0] + base * 16);
      }
    }
    // B: 1 chunk per thread (unconditional)
    {
      const uint16_t* wk = Wt + (size_t)k * 128 * CIN + q * 32;
      const int row = t >> 2;
      const int sw = (t & 3) ^ ((row >> 1) & 3);
      gld_lds16((const void*)(wk + (size_t)row * CIN + sw * 8),
                (char*)&Bs[nb][0] + (w * 64) * 16);
    }
  };

  stage(0, 0);
  __syncthreads();

  int cur = 0;
  for (int s = 0; s < S; ++s) {
    if (s + 1 < S) stage(s + 1, cur ^ 1);
    const int k = s / QH;
    const int m0 = msk[k * 16 + wr * 4 + 0];
    const int m1 = msk[k * 16 + wr * 4 + 1];
    const int m2 = msk[k * 16 + wr * 4 + 2];
    const int m3 = msk[k * 16 + wr * 4 + 3];
    if (m0 | m1 | m2 | m3) {
      const char* Ab = (const char*)&As[cur][0];
      const char* Bb = (const char*)&Bs[cur][0];
      bf16x8 a[4], b[4];
      const int cl = lane >> 4;
      #pragma unroll
      for (int n = 0; n < 4; ++n) {
        int row = wc * 64 + n * 16 + (lane & 15);
        b[n] = *(const bf16x8*)(Bb + row * 64 + ((cl ^ ((row >> 1) & 3)) * 16));
      }
      const int mv[4] = {m0, m1, m2, m3};
      #pragma unroll
      for (int m = 0; m < 4; ++m) {
        if (mv[m]) {
          int row = wr * 64 + m * 16 + (lane & 15);
          a[m] = *(const bf16x8*)(Ab + row * 64 + ((cl ^ ((row >> 1) & 3)) * 16));
          #pragma unroll
          for (int n = 0; n < 4; ++n)
            acc[m][n] = __builtin_amdgcn_mfma_f32_16x16x32_bf16(a[m], b[n], acc[m][n], 0, 0, 0);
        }
      }
    }
    __syncthreads();
    cur ^= 1;
  }

  // epilogue: C/D frag: col = lane&15, row = (lane>>4)*4 + reg
  #pragma unroll
  for (int m = 0; m < 4; ++m) {
    int rbase = n0 + wr * 64 + m * 16 + ((lane >> 4) << 2);
    #pragma unroll
    for (int r = 0; r < 4; ++r) {
      int gr = rbase + r;
      if (gr < Nout) {
        #pragma unroll
        for (int n = 0; n < 4; ++n) {
          int col = wc * 64 + n * 16 + (lane & 15);
          float v = acc[m][n][r] + bias[col];
          if (RELU) v = fmaxf(v, 0.f);
          if (OUTF32) outf[(size_t)gr * 128 + col] = v;
          if (SHADOW) outb[(size_t)gr * 128 + col] = (uint16_t)f2bf(v);
        }
      }
    }
  }
}

// =====================================================================
// FALLBACK (round-1 proven path): reg-staged serial sconv
// =====================================================================
template <int CIN, bool IN_F32, bool RELU, bool WF32>
__global__ __launch_bounds__(256) void sconv_mfma_kernel(
    const void* __restrict__ fin, const int* __restrict__ kmap,
    const uint16_t* __restrict__ Wt, const float* __restrict__ bias,
    void* __restrict__ outp, int Nout) {
  constexpr int ROWB = CIN * 2;
  constexpr int CHR  = CIN / 8;
  constexpr int CPT  = (128 * CHR) / 256;
  __shared__ __align__(16) uint16_t As[128 * CIN];
  __shared__ __align__(16) uint16_t Bs[128 * CIN];
  const int t = threadIdx.x;
  const int lane = t & 63, w = t >> 6;
  const int wr = w >> 1, wc = w & 1;
  const int n0 = blockIdx.x * 128;
  f32x4 acc[4][4] = {};
  for (int k = 0; k < 27; ++k) {
    const int* __restrict__ km = kmap + (size_t)k * Nout;
    #pragma unroll
    for (int j = 0; j < CPT; ++j) {
      int c = t + j * 256;
      int row = c / CHR, c16 = c - row * CHR;
      int n = n0 + row;
      int idx = (n < Nout) ? km[n] : -1;
      int4 v = {0, 0, 0, 0};
      if (idx >= 0) {
        if (IN_F32) {
          const float* src = (const float*)fin + (size_t)idx * CIN + c16 * 8;
          float4 lo = *(const float4*)src;
          float4 hi = *(const float4*)(src + 4);
          v.x = (int)(f2bf(lo.x) | (f2bf(lo.y) << 16));
          v.y = (int)(f2bf(lo.z) | (f2bf(lo.w) << 16));
          v.z = (int)(f2bf(hi.x) | (f2bf(hi.y) << 16));
          v.w = (int)(f2bf(hi.z) | (f2bf(hi.w) << 16));
        } else {
          v = *(const int4*)((const uint16_t*)fin + (size_t)idx * CIN + c16 * 8);
        }
      }
      *(int4*)((char*)As + row * ROWB + ((c16 * 16) ^ ((row & 7) << 4))) = v;
    }
    const uint16_t* __restrict__ wkp = Wt + (size_t)k * 128 * CIN;
    #pragma unroll
    for (int j = 0; j < CPT; ++j) {
      int c = t + j * 256;
      int row = c / CHR, c16 = c - row * CHR;
      int4 v = *(const int4*)(wkp + row * CIN + c16 * 8);
      *(int4*)((char*)Bs + row * ROWB + ((c16 * 16) ^ ((row & 7) << 4))) = v;
    }
    __syncthreads();
    #pragma unroll
    for (int kk = 0; kk < CIN / 32; ++kk) {
      const int kb = (kk * 32 + ((lane >> 4) * 8)) * 2;
      bf16x8 a[4], b[4];
      #pragma unroll
      for (int m = 0; m < 4; ++m) {
        int row = wr * 64 + m * 16 + (lane & 15);
        a[m] = *(const bf16x8*)((const char*)As + row * ROWB + (kb ^ ((row & 7) << 4)));
      }
      #pragma unroll
      for (int n = 0; n < 4; ++n) {
        int row = wc * 64 + n * 16 + (lane & 15);
        b[n] = *(const bf16x8*)((const char*)Bs + row * ROWB + (kb ^ ((row & 7) << 4)));
      }
      #pragma unroll
      for (int m = 0; m < 4; ++m)
        #pragma unroll
        for (int n = 0; n < 4; ++n)
          acc[m][n] = __builtin_amdgcn_mfma_f32_16x16x32_bf16(a[m], b[n], acc[m][n], 0, 0, 0);
    }
    __syncthreads();
  }
  #pragma unroll
  for (int m = 0; m < 4; ++m) {
    int rbase = n0 + wr * 64 + m * 16 + ((lane >> 4) << 2);
    #pragma unroll
    for (int r = 0; r < 4; ++r) {
      int gr = rbase + r;
      if (gr < Nout) {
        #pragma unroll
        for (int n = 0; n < 4; ++n) {
          int col = wc * 64 + n * 16 + (lane & 15);
          float v = acc[m][n][r] + bias[col];
          if (RELU) v = fmaxf(v, 0.f);
          if (WF32) ((float*)outp)[(size_t)gr * 128 + col] = v;
          else      ((uint16_t*)outp)[(size_t)gr * 128 + col] = (uint16_t)f2bf(v);
        }
      }
    }
  }
}

extern "C" void kernel_launch(void* const* d_in, const int* in_sizes, int n_in,
                              void* d_out, int out_size, void* d_ws, size_t ws_size,
                              hipStream_t stream) {
  const float* x    = (const float*)d_in[0];
  const int*   km0  = (const int*)d_in[1];
  const int*   kmd0 = (const int*)d_in[2];
  const int*   km1  = (const int*)d_in[3];
  const int*   kmd1 = (const int*)d_in[4];
  const int*   km2  = (const int*)d_in[5];
  const int*   kmd2 = (const int*)d_in[6];
  const float* W0   = (const float*)d_in[7];
  const float* b0   = (const float*)d_in[8];
  const float* Wd0  = (const float*)d_in[9];
  const float* bd0  = (const float*)d_in[10];
  const float* W1   = (const float*)d_in[11];
  const float* b1   = (const float*)d_in[12];
  const float* Wd1  = (const float*)d_in[13];
  const float* bd1  = (const float*)d_in[14];
  const float* W2   = (const float*)d_in[15];
  const float* b2   = (const float*)d_in[16];
  const float* Wd2  = (const float*)d_in[17];
  const float* bd2  = (const float*)d_in[18];

  const int N0 = in_sizes[1] / 27;
  const int N1 = in_sizes[2] / 27;
  const int N2 = in_sizes[4] / 27;
  const int N3 = in_sizes[6] / 27;

  float* out2 = (float*)d_out;
  float* out1 = out2 + (size_t)N3 * 128;
  float* out0 = out1 + (size_t)N2 * 128;

  const size_t wsz_d0 = (size_t)27 * 64 * 128 * 2;
  const size_t wsz    = (size_t)27 * 128 * 128 * 2;
  const size_t bufA_b = 2 * ((size_t)N0 * 64 > (size_t)N1 * 128 ? (size_t)N0 * 64 : (size_t)N1 * 128);
  const size_t bufB_b = 2 * (size_t)((N1 > N2 ? N1 : N2)) * 128;

  char* p = (char*)d_ws;
  uint16_t* zp    = (uint16_t*)p; p += 512;
  uint16_t* Wt_d0 = (uint16_t*)p; p += wsz_d0;
  uint16_t* Wt_1  = (uint16_t*)p; p += wsz;
  uint16_t* Wt_d1 = (uint16_t*)p; p += wsz;
  uint16_t* Wt_2  = (uint16_t*)p; p += wsz;
  uint16_t* Wt_d2 = (uint16_t*)p; p += wsz;
  uint16_t* bufA  = (uint16_t*)p; p += bufA_b;
  uint16_t* bufB  = (uint16_t*)p;

  const size_t needed_new = 512 + wsz_d0 + 4 * wsz + bufA_b + bufB_b;

  // fused weight prep (all 5 transposes + zp zeroing), one launch
  {
    const int total = 27 * 128 * (64 + 4 * 128);
    wprep_all_kernel<<<dim3((total + 255) / 256), dim3(256), 0, stream>>>(
        Wd0, W1, Wd1, W2, Wd2, Wt_d0, Wt_1, Wt_d1, Wt_2, Wt_d2, zp);
  }

  if (ws_size >= needed_new) {
    // conv0: x -> h0 bf16 (bufA)
    conv0_kernel<<<dim3((N0 + 255) / 256), dim3(256), 0, stream>>>(x, km0, W0, b0, bufA, N0);
    // down0: h0(bufA) -> out0 f32 + bf16 shadow (bufB), relu
    sconv_pipe2_kernel<64, true, true, true>
        <<<dim3((N1 + 255) / 256), dim3(512), 0, stream>>>(bufA, kmd0, Wt_d0, bd0, out0, bufB, zp, N1);
    // conv1: out0b(bufB) -> h1 bf16 (bufA)
    sconv_pipe2_kernel<128, false, false, true>
        <<<dim3((N1 + 255) / 256), dim3(512), 0, stream>>>(bufB, km1, Wt_1, b1, nullptr, bufA, zp, N1);
    // down1: h1(bufA) -> out1 f32 + bf16 shadow (bufB), relu
    sconv_pipe2_kernel<128, true, true, true>
        <<<dim3((N2 + 255) / 256), dim3(512), 0, stream>>>(bufA, kmd1, Wt_d1, bd1, out1, bufB, zp, N2);
    // conv2: out1b(bufB) -> h2 bf16 (bufA)
    sconv_pipe2_kernel<128, false, false, true>
        <<<dim3((N2 + 255) / 256), dim3(512), 0, stream>>>(bufB, km2, Wt_2, b2, nullptr, bufA, zp, N2);
    // down2: h2(bufA) -> out2 f32 (no relu)
    sconv_pipe2_kernel<128, true, false, false>
        <<<dim3((N3 + 255) / 256), dim3(512), 0, stream>>>(bufA, kmd2, Wt_d2, bd2, out2, nullptr, zp, N3);
  } else {
    uint16_t* hbuf = (uint16_t*)((char*)d_ws + 512 + wsz_d0 + 4 * wsz);
    conv0_kernel<<<dim3((N0 + 255) / 256), dim3(256), 0, stream>>>(x, km0, W0, b0, hbuf, N0);
    sconv_mfma_kernel<64, false, true, true>
        <<<dim3((N1 + 127) / 128), dim3(256), 0, stream>>>(hbuf, kmd0, Wt_d0, bd0, out0, N1);
    sconv_mfma_kernel<128, true, false, false>
        <<<dim3((N1 + 127) / 128), dim3(256), 0, stream>>>(out0, km1, Wt_1, b1, hbuf, N1);
    sconv_mfma_kernel<128, false, true, true>
        <<<dim3((N2 + 127) / 128), dim3(256), 0, stream>>>(hbuf, kmd1, Wt_d1, bd1, out1, N2);
    sconv_mfma_kernel<128, true, false, false>
        <<<dim3((N2 + 127) / 128), dim3(256), 0, stream>>>(out1, km2, Wt_2, b2, hbuf, N2);
    sconv_mfma_kernel<128, false, false, true>
        <<<dim3((N3 + 127) / 128), dim3(256), 0, stream>>>(hbuf, kmd2, Wt_d2, bd2, out2, N3);
  }
}

// Round 13
// 1028.217 us; speedup vs baseline: 1.0802x; 1.0802x over previous
//
#include <hip/hip_runtime.h>
#include <stdint.h>

typedef __bf16 bf16x8 __attribute__((ext_vector_type(8)));
typedef float f32x4 __attribute__((ext_vector_type(4)));

__device__ __forceinline__ uint32_t f2bf(float f) {
  uint32_t u = __builtin_bit_cast(uint32_t, f);
  return (u + 0x7fffu + ((u >> 16) & 1u)) >> 16;
}

__device__ __forceinline__ void gld_lds16(const void* g, void* l) {
  __builtin_amdgcn_global_load_lds(
      (const __attribute__((address_space(1))) void*)g,
      (__attribute__((address_space(3))) void*)l, 16, 0, 0);
}

// ---- fused weight prep: all 5 transposes + zp zeroing in one launch.
__global__ __launch_bounds__(256) void wprep_all_kernel(
    const float* __restrict__ Wd0, const float* __restrict__ W1,
    const float* __restrict__ Wd1, const float* __restrict__ W2,
    const float* __restrict__ Wd2,
    uint16_t* __restrict__ Td0, uint16_t* __restrict__ T1,
    uint16_t* __restrict__ Td1, uint16_t* __restrict__ T2,
    uint16_t* __restrict__ Td2, uint16_t* __restrict__ zp) {
  int i = blockIdx.x * 256 + threadIdx.x;
  if (i < 256) zp[i] = 0;
  constexpr int S0 = 27 * 64 * 128;
  constexpr int S1 = 27 * 128 * 128;
  if (i < S0) {
    int k = i >> 13, r = i & 8191;
    int co = r >> 6, ci = r & 63;
    Td0[i] = (uint16_t)f2bf(Wd0[(k * 64 + ci) * 128 + co]);
    return;
  }
  i -= S0;
  const float* src;
  uint16_t* dst;
  if (i < S1)          { src = W1;  dst = T1; }
  else if (i < 2 * S1) { src = Wd1; dst = Td1; i -= S1; }
  else if (i < 3 * S1) { src = W2;  dst = T2;  i -= 2 * S1; }
  else if (i < 4 * S1) { src = Wd2; dst = Td2; i -= 3 * S1; }
  else return;
  int k = i >> 14, r = i & 16383;
  int co = r >> 7, ci = r & 127;
  dst[i] = (uint16_t)f2bf(src[(k * 128 + ci) * 128 + co]);
}

// ---- conv0: Cin=3 -> Cout=64, fp32 in, bf16 out. Point-per-thread.
__global__ __launch_bounds__(256) void conv0_kernel(
    const float* __restrict__ x, const int* __restrict__ km,
    const float* __restrict__ W0, const float* __restrict__ b0,
    uint16_t* __restrict__ h0, int N) {
  __shared__ float Ws[27 * 192 + 64];
  for (int i = threadIdx.x; i < 27 * 192; i += 256) Ws[i] = W0[i];
  if (threadIdx.x < 64) Ws[27 * 192 + threadIdx.x] = b0[threadIdx.x];
  __syncthreads();
  const int n = blockIdx.x * 256 + threadIdx.x;
  if (n >= N) return;

  int idx[27];
  #pragma unroll
  for (int k = 0; k < 27; ++k) idx[k] = km[(size_t)k * N + n];

  f32x4 acc[16];
  #pragma unroll
  for (int c = 0; c < 16; ++c) acc[c] = *(const f32x4*)&Ws[27 * 192 + c * 4];

  #pragma unroll
  for (int k = 0; k < 27; ++k) {
    if (idx[k] >= 0) {
      const float* xr = x + (size_t)idx[k] * 3;
      const float x0 = xr[0], x1 = xr[1], x2 = xr[2];
      const float* wk = Ws + k * 192;
      #pragma unroll
      for (int c = 0; c < 16; ++c) {
        const f32x4 w0 = *(const f32x4*)(wk + c * 4);
        const f32x4 w1 = *(const f32x4*)(wk + 64 + c * 4);
        const f32x4 w2 = *(const f32x4*)(wk + 128 + c * 4);
        acc[c] += x0 * w0 + x1 * w1 + x2 * w2;
      }
    }
  }

  uint16_t* out = h0 + (size_t)n * 64;
  #pragma unroll
  for (int g = 0; g < 8; ++g) {
    int4 v;
    v.x = (int)(f2bf(acc[g * 2][0]) | (f2bf(acc[g * 2][1]) << 16));
    v.y = (int)(f2bf(acc[g * 2][2]) | (f2bf(acc[g * 2][3]) << 16));
    v.z = (int)(f2bf(acc[g * 2 + 1][0]) | (f2bf(acc[g * 2 + 1][1]) << 16));
    v.w = (int)(f2bf(acc[g * 2 + 1][2]) | (f2bf(acc[g * 2 + 1][3]) << 16));
    *(int4*)(out + g * 8) = v;
  }
}

// =====================================================================
// CHAMPION (r5/r11 structure). MASKED=false: byte-identical to r11.
// MASKED=true (down0 only, ~2% density, 74% dead 16-row groups):
// per-(tap,group) validity masks skip A-stage + a-ds_read + MFMAs.
// =====================================================================
template <int CIN, bool OUTF32, bool RELU, bool SHADOW, bool MASKED>
__global__ __launch_bounds__(512, 4) void sconv_pipe2_kernel(
    const uint16_t* __restrict__ fin, const int* __restrict__ kmap,
    const uint16_t* __restrict__ Wt, const float* __restrict__ bias,
    float* __restrict__ outf, uint16_t* __restrict__ outb,
    const uint16_t* __restrict__ zp, int Nout) {
  constexpr int QH = CIN / 32;   // 32-col quarters per row
  constexpr int S = 27 * QH;
  __shared__ __align__(16) uint16_t As[2][256 * 32];
  __shared__ __align__(16) uint16_t Bs[2][128 * 32];
  __shared__ int idxs[27 * 256];
  __shared__ unsigned char msk[27 * 16];   // used only if MASKED

  const int t = threadIdx.x;
  const int lane = t & 63, w = t >> 6;
  const int wr = w >> 1, wc = w & 1;

  // bijective XCD-chunked swizzle (m204)
  const int nwg = gridDim.x;
  int bid = blockIdx.x;
  if (nwg >= 8) {
    const int q = nwg >> 3, r = nwg & 7;
    const int xcd = bid & 7, pos = bid >> 3;
    bid = (xcd < r ? xcd * (q + 1) : r * (q + 1) + (xcd - r) * q) + pos;
  }
  const int n0 = bid * 256;

  for (int i = t; i < 27 * 256; i += 512) {
    int n = n0 + (i & 255);
    idxs[i] = (n < Nout) ? kmap[(size_t)(i >> 8) * Nout + n] : -1;
  }
  __syncthreads();

  if (MASKED) {
    if (t < 27 * 16) {
      const int* ip = &idxs[(t >> 4) * 256 + (t & 15) * 16];
      int any = 0;
      #pragma unroll
      for (int j = 0; j < 16; ++j) any |= (ip[j] >= 0) ? 1 : 0;
      msk[t] = (unsigned char)any;
    }
    __syncthreads();
  }

  f32x4 acc[4][4] = {};

  auto stage = [&](int ss, int nb) {
    const int k = ss / QH;
    const int q = ss & (QH - 1);
    // A: 256 rows x 32 cols bf16 = 1024 x 16B chunks; 2 per thread.
    #pragma unroll
    for (int j = 0; j < 2; ++j) {
      if (!MASKED || msk[k * 16 + w + j * 8]) {
        const int base = w * 64 + j * 512;
        const int row = (base >> 2) + (lane >> 2);
        const int sw = (lane & 3) ^ ((row >> 1) & 3);
        const int idx = idxs[k * 256 + row];
        const void* srcA = (idx >= 0)
            ? (const void*)(fin + (size_t)idx * CIN + q * 32 + sw * 8)
            : (const void*)zp;
        gld_lds16(srcA, (char*)&As[nb][0] + base * 16);
      }
    }
    // B: 128 rows x 32 cols = 512 chunks; 1 per thread
    {
      const uint16_t* wk = Wt + (size_t)k * 128 * CIN + q * 32;
      const int row = t >> 2;
      const int sw = (t & 3) ^ ((row >> 1) & 3);
      gld_lds16((const void*)(wk + (size_t)row * CIN + sw * 8),
                (char*)&Bs[nb][0] + (w * 64) * 16);
    }
  };

  stage(0, 0);
  __syncthreads();

  int cur = 0;
  for (int s = 0; s < S; ++s) {
    if (s + 1 < S) stage(s + 1, cur ^ 1);
    const char* Ab = (const char*)&As[cur][0];
    const char* Bb = (const char*)&Bs[cur][0];
    const int cl = lane >> 4;
    if (MASKED) {
      const int k = s / QH;
      const int m0 = msk[k * 16 + wr * 4 + 0];
      const int m1 = msk[k * 16 + wr * 4 + 1];
      const int m2 = msk[k * 16 + wr * 4 + 2];
      const int m3 = msk[k * 16 + wr * 4 + 3];
      if (m0 | m1 | m2 | m3) {
        bf16x8 a, b[4];
        #pragma unroll
        for (int n = 0; n < 4; ++n) {
          int row = wc * 64 + n * 16 + (lane & 15);
          b[n] = *(const bf16x8*)(Bb + row * 64 + ((cl ^ ((row >> 1) & 3)) * 16));
        }
        const int mv[4] = {m0, m1, m2, m3};
        #pragma unroll
        for (int m = 0; m < 4; ++m) {
          if (mv[m]) {
            int row = wr * 64 + m * 16 + (lane & 15);
            a = *(const bf16x8*)(Ab + row * 64 + ((cl ^ ((row >> 1) & 3)) * 16));
            #pragma unroll
            for (int n = 0; n < 4; ++n)
              acc[m][n] = __builtin_amdgcn_mfma_f32_16x16x32_bf16(a, b[n], acc[m][n], 0, 0, 0);
          }
        }
      }
    } else {
      bf16x8 a[4], b[4];
      #pragma unroll
      for (int m = 0; m < 4; ++m) {
        int row = wr * 64 + m * 16 + (lane & 15);
        a[m] = *(const bf16x8*)(Ab + row * 64 + ((cl ^ ((row >> 1) & 3)) * 16));
      }
      #pragma unroll
      for (int n = 0; n < 4; ++n) {
        int row = wc * 64 + n * 16 + (lane & 15);
        b[n] = *(const bf16x8*)(Bb + row * 64 + ((cl ^ ((row >> 1) & 3)) * 16));
      }
      #pragma unroll
      for (int m = 0; m < 4; ++m)
        #pragma unroll
        for (int n = 0; n < 4; ++n)
          acc[m][n] = __builtin_amdgcn_mfma_f32_16x16x32_bf16(a[m], b[n], acc[m][n], 0, 0, 0);
    }
    __syncthreads();
    cur ^= 1;
  }

  // epilogue: C/D frag: col = lane&15, row = (lane>>4)*4 + reg
  #pragma unroll
  for (int m = 0; m < 4; ++m) {
    int rbase = n0 + wr * 64 + m * 16 + ((lane >> 4) << 2);
    #pragma unroll
    for (int r = 0; r < 4; ++r) {
      int gr = rbase + r;
      if (gr < Nout) {
        #pragma unroll
        for (int n = 0; n < 4; ++n) {
          int col = wc * 64 + n * 16 + (lane & 15);
          float v = acc[m][n][r] + bias[col];
          if (RELU) v = fmaxf(v, 0.f);
          if (OUTF32) outf[(size_t)gr * 128 + col] = v;
          if (SHADOW) outb[(size_t)gr * 128 + col] = (uint16_t)f2bf(v);
        }
      }
    }
  }
}

// =====================================================================
// FALLBACK (round-1 proven path): reg-staged serial sconv
// =====================================================================
template <int CIN, bool IN_F32, bool RELU, bool WF32>
__global__ __launch_bounds__(256) void sconv_mfma_kernel(
    const void* __restrict__ fin, const int* __restrict__ kmap,
    const uint16_t* __restrict__ Wt, const float* __restrict__ bias,
    void* __restrict__ outp, int Nout) {
  constexpr int ROWB = CIN * 2;
  constexpr int CHR  = CIN / 8;
  constexpr int CPT  = (128 * CHR) / 256;
  __shared__ __align__(16) uint16_t As[128 * CIN];
  __shared__ __align__(16) uint16_t Bs[128 * CIN];
  const int t = threadIdx.x;
  const int lane = t & 63, w = t >> 6;
  const int wr = w >> 1, wc = w & 1;
  const int n0 = blockIdx.x * 128;
  f32x4 acc[4][4] = {};
  for (int k = 0; k < 27; ++k) {
    const int* __restrict__ km = kmap + (size_t)k * Nout;
    #pragma unroll
    for (int j = 0; j < CPT; ++j) {
      int c = t + j * 256;
      int row = c / CHR, c16 = c - row * CHR;
      int n = n0 + row;
      int idx = (n < Nout) ? km[n] : -1;
      int4 v = {0, 0, 0, 0};
      if (idx >= 0) {
        if (IN_F32) {
          const float* src = (const float*)fin + (size_t)idx * CIN + c16 * 8;
          float4 lo = *(const float4*)src;
          float4 hi = *(const float4*)(src + 4);
          v.x = (int)(f2bf(lo.x) | (f2bf(lo.y) << 16));
          v.y = (int)(f2bf(lo.z) | (f2bf(lo.w) << 16));
          v.z = (int)(f2bf(hi.x) | (f2bf(hi.y) << 16));
          v.w = (int)(f2bf(hi.z) | (f2bf(hi.w) << 16));
        } else {
          v = *(const int4*)((const uint16_t*)fin + (size_t)idx * CIN + c16 * 8);
        }
      }
      *(int4*)((char*)As + row * ROWB + ((c16 * 16) ^ ((row & 7) << 4))) = v;
    }
    const uint16_t* __restrict__ wkp = Wt + (size_t)k * 128 * CIN;
    #pragma unroll
    for (int j = 0; j < CPT; ++j) {
      int c = t + j * 256;
      int row = c / CHR, c16 = c - row * CHR;
      int4 v = *(const int4*)(wkp + row * CIN + c16 * 8);
      *(int4*)((char*)Bs + row * ROWB + ((c16 * 16) ^ ((row & 7) << 4))) = v;
    }
    __syncthreads();
    #pragma unroll
    for (int kk = 0; kk < CIN / 32; ++kk) {
      const int kb = (kk * 32 + ((lane >> 4) * 8)) * 2;
      bf16x8 a[4], b[4];
      #pragma unroll
      for (int m = 0; m < 4; ++m) {
        int row = wr * 64 + m * 16 + (lane & 15);
        a[m] = *(const bf16x8*)((const char*)As + row * ROWB + (kb ^ ((row & 7) << 4)));
      }
      #pragma unroll
      for (int n = 0; n < 4; ++n) {
        int row = wc * 64 + n * 16 + (lane & 15);
        b[n] = *(const bf16x8*)((const char*)Bs + row * ROWB + (kb ^ ((row & 7) << 4)));
      }
      #pragma unroll
      for (int m = 0; m < 4; ++m)
        #pragma unroll
        for (int n = 0; n < 4; ++n)
          acc[m][n] = __builtin_amdgcn_mfma_f32_16x16x32_bf16(a[m], b[n], acc[m][n], 0, 0, 0);
    }
    __syncthreads();
  }
  #pragma unroll
  for (int m = 0; m < 4; ++m) {
    int rbase = n0 + wr * 64 + m * 16 + ((lane >> 4) << 2);
    #pragma unroll
    for (int r = 0; r < 4; ++r) {
      int gr = rbase + r;
      if (gr < Nout) {
        #pragma unroll
        for (int n = 0; n < 4; ++n) {
          int col = wc * 64 + n * 16 + (lane & 15);
          float v = acc[m][n][r] + bias[col];
          if (RELU) v = fmaxf(v, 0.f);
          if (WF32) ((float*)outp)[(size_t)gr * 128 + col] = v;
          else      ((uint16_t*)outp)[(size_t)gr * 128 + col] = (uint16_t)f2bf(v);
        }
      }
    }
  }
}

extern "C" void kernel_launch(void* const* d_in, const int* in_sizes, int n_in,
                              void* d_out, int out_size, void* d_ws, size_t ws_size,
                              hipStream_t stream) {
  const float* x    = (const float*)d_in[0];
  const int*   km0  = (const int*)d_in[1];
  const int*   kmd0 = (const int*)d_in[2];
  const int*   km1  = (const int*)d_in[3];
  const int*   kmd1 = (const int*)d_in[4];
  const int*   km2  = (const int*)d_in[5];
  const int*   kmd2 = (const int*)d_in[6];
  const float* W0   = (const float*)d_in[7];
  const float* b0   = (const float*)d_in[8];
  const float* Wd0  = (const float*)d_in[9];
  const float* bd0  = (const float*)d_in[10];
  const float* W1   = (const float*)d_in[11];
  const float* b1   = (const float*)d_in[12];
  const float* Wd1  = (const float*)d_in[13];
  const float* bd1  = (const float*)d_in[14];
  const float* W2   = (const float*)d_in[15];
  const float* b2   = (const float*)d_in[16];
  const float* Wd2  = (const float*)d_in[17];
  const float* bd2  = (const float*)d_in[18];

  const int N0 = in_sizes[1] / 27;
  const int N1 = in_sizes[2] / 27;
  const int N2 = in_sizes[4] / 27;
  const int N3 = in_sizes[6] / 27;

  float* out2 = (float*)d_out;
  float* out1 = out2 + (size_t)N3 * 128;
  float* out0 = out1 + (size_t)N2 * 128;

  const size_t wsz_d0 = (size_t)27 * 64 * 128 * 2;
  const size_t wsz    = (size_t)27 * 128 * 128 * 2;
  const size_t bufA_b = 2 * ((size_t)N0 * 64 > (size_t)N1 * 128 ? (size_t)N0 * 64 : (size_t)N1 * 128);
  const size_t bufB_b = 2 * (size_t)((N1 > N2 ? N1 : N2)) * 128;

  char* p = (char*)d_ws;
  uint16_t* zp    = (uint16_t*)p; p += 512;
  uint16_t* Wt_d0 = (uint16_t*)p; p += wsz_d0;
  uint16_t* Wt_1  = (uint16_t*)p; p += wsz;
  uint16_t* Wt_d1 = (uint16_t*)p; p += wsz;
  uint16_t* Wt_2  = (uint16_t*)p; p += wsz;
  uint16_t* Wt_d2 = (uint16_t*)p; p += wsz;
  uint16_t* bufA  = (uint16_t*)p; p += bufA_b;
  uint16_t* bufB  = (uint16_t*)p;

  const size_t needed_new = 512 + wsz_d0 + 4 * wsz + bufA_b + bufB_b;

  // fused weight prep (all 5 transposes + zp zeroing), one launch
  {
    const int total = 27 * 128 * (64 + 4 * 128);
    wprep_all_kernel<<<dim3((total + 255) / 256), dim3(256), 0, stream>>>(
        Wd0, W1, Wd1, W2, Wd2, Wt_d0, Wt_1, Wt_d1, Wt_2, Wt_d2, zp);
  }

  if (ws_size >= needed_new) {
    // conv0: x -> h0 bf16 (bufA)
    conv0_kernel<<<dim3((N0 + 255) / 256), dim3(256), 0, stream>>>(x, km0, W0, b0, bufA, N0);
    // down0: h0(bufA) -> out0 f32 + bf16 shadow (bufB), relu — MASKED (2% density)
    sconv_pipe2_kernel<64, true, true, true, true>
        <<<dim3((N1 + 255) / 256), dim3(512), 0, stream>>>(bufA, kmd0, Wt_d0, bd0, out0, bufB, zp, N1);
    // conv1: out0b(bufB) -> h1 bf16 (bufA) — unmasked (r11 exact)
    sconv_pipe2_kernel<128, false, false, true, false>
        <<<dim3((N1 + 255) / 256), dim3(512), 0, stream>>>(bufB, km1, Wt_1, b1, nullptr, bufA, zp, N1);
    // down1: h1(bufA) -> out1 f32 + bf16 shadow (bufB), relu — unmasked
    sconv_pipe2_kernel<128, true, true, true, false>
        <<<dim3((N2 + 255) / 256), dim3(512), 0, stream>>>(bufA, kmd1, Wt_d1, bd1, out1, bufB, zp, N2);
    // conv2: out1b(bufB) -> h2 bf16 (bufA) — unmasked
    sconv_pipe2_kernel<128, false, false, true, false>
        <<<dim3((N2 + 255) / 256), dim3(512), 0, stream>>>(bufB, km2, Wt_2, b2, nullptr, bufA, zp, N2);
    // down2: h2(bufA) -> out2 f32 (no relu) — unmasked
    sconv_pipe2_kernel<128, true, false, false, false>
        <<<dim3((N3 + 255) / 256), dim3(512), 0, stream>>>(bufA, kmd2, Wt_d2, bd2, out2, nullptr, zp, N3);
  } else {
    uint16_t* hbuf = (uint16_t*)((char*)d_ws + 512 + wsz_d0 + 4 * wsz);
    conv0_kernel<<<dim3((N0 + 255) / 256), dim3(256), 0, stream>>>(x, km0, W0, b0, hbuf, N0);
    sconv_mfma_kernel<64, false, true, true>
        <<<dim3((N1 + 127) / 128), dim3(256), 0, stream>>>(hbuf, kmd0, Wt_d0, bd0, out0, N1);
    sconv_mfma_kernel<128, true, false, false>
        <<<dim3((N1 + 127) / 128), dim3(256), 0, stream>>>(out0, km1, Wt_1, b1, hbuf, N1);
    sconv_mfma_kernel<128, false, true, true>
        <<<dim3((N2 + 127) / 128), dim3(256), 0, stream>>>(hbuf, kmd1, Wt_d1, bd1, out1, N2);
    sconv_mfma_kernel<128, true, false, false>
        <<<dim3((N2 + 127) / 128), dim3(256), 0, stream>>>(out1, km2, Wt_2, b2, hbuf, N2);
    sconv_mfma_kernel<128, false, false, true>
        <<<dim3((N3 + 127) / 128), dim3(256), 0, stream>>>(hbuf, kmd2, Wt_d2, bd2, out2, N3);
  }
}

// Round 14
// 1014.861 us; speedup vs baseline: 1.0944x; 1.0132x over previous
//
#include <hip/hip_runtime.h>
#include <stdint.h>

typedef __bf16 bf16x8 __attribute__((ext_vector_type(8)));
typedef float f32x4 __attribute__((ext_vector_type(4)));

__device__ __forceinline__ uint32_t f2bf(float f) {
  uint32_t u = __builtin_bit_cast(uint32_t, f);
  return (u + 0x7fffu + ((u >> 16) & 1u)) >> 16;
}

__device__ __forceinline__ void gld_lds16(const void* g, void* l) {
  __builtin_amdgcn_global_load_lds(
      (const __attribute__((address_space(1))) void*)g,
      (__attribute__((address_space(3))) void*)l, 16, 0, 0);
}

// ---- fused weight prep: all 5 transposes + zp zeroing in one launch.
__global__ __launch_bounds__(256) void wprep_all_kernel(
    const float* __restrict__ Wd0, const float* __restrict__ W1,
    const float* __restrict__ Wd1, const float* __restrict__ W2,
    const float* __restrict__ Wd2,
    uint16_t* __restrict__ Td0, uint16_t* __restrict__ T1,
    uint16_t* __restrict__ Td1, uint16_t* __restrict__ T2,
    uint16_t* __restrict__ Td2, uint16_t* __restrict__ zp) {
  int i = blockIdx.x * 256 + threadIdx.x;
  if (i < 256) zp[i] = 0;
  constexpr int S0 = 27 * 64 * 128;
  constexpr int S1 = 27 * 128 * 128;
  if (i < S0) {
    int k = i >> 13, r = i & 8191;
    int co = r >> 6, ci = r & 63;
    Td0[i] = (uint16_t)f2bf(Wd0[(k * 64 + ci) * 128 + co]);
    return;
  }
  i -= S0;
  const float* src;
  uint16_t* dst;
  if (i < S1)          { src = W1;  dst = T1; }
  else if (i < 2 * S1) { src = Wd1; dst = Td1; i -= S1; }
  else if (i < 3 * S1) { src = W2;  dst = T2;  i -= 2 * S1; }
  else if (i < 4 * S1) { src = Wd2; dst = Td2; i -= 3 * S1; }
  else return;
  int k = i >> 14, r = i & 16383;
  int co = r >> 7, ci = r & 127;
  dst[i] = (uint16_t)f2bf(src[(k * 128 + ci) * 128 + co]);
}

// ---- conv0: Cin=3 -> Cout=64, fp32 in, bf16 out. Point-per-thread.
__global__ __launch_bounds__(256) void conv0_kernel(
    const float* __restrict__ x, const int* __restrict__ km,
    const float* __restrict__ W0, const float* __restrict__ b0,
    uint16_t* __restrict__ h0, int N) {
  __shared__ float Ws[27 * 192 + 64];
  for (int i = threadIdx.x; i < 27 * 192; i += 256) Ws[i] = W0[i];
  if (threadIdx.x < 64) Ws[27 * 192 + threadIdx.x] = b0[threadIdx.x];
  __syncthreads();
  const int n = blockIdx.x * 256 + threadIdx.x;
  if (n >= N) return;

  int idx[27];
  #pragma unroll
  for (int k = 0; k < 27; ++k) idx[k] = km[(size_t)k * N + n];

  f32x4 acc[16];
  #pragma unroll
  for (int c = 0; c < 16; ++c) acc[c] = *(const f32x4*)&Ws[27 * 192 + c * 4];

  #pragma unroll
  for (int k = 0; k < 27; ++k) {
    if (idx[k] >= 0) {
      const float* xr = x + (size_t)idx[k] * 3;
      const float x0 = xr[0], x1 = xr[1], x2 = xr[2];
      const float* wk = Ws + k * 192;
      #pragma unroll
      for (int c = 0; c < 16; ++c) {
        const f32x4 w0 = *(const f32x4*)(wk + c * 4);
        const f32x4 w1 = *(const f32x4*)(wk + 64 + c * 4);
        const f32x4 w2 = *(const f32x4*)(wk + 128 + c * 4);
        acc[c] += x0 * w0 + x1 * w1 + x2 * w2;
      }
    }
  }

  uint16_t* out = h0 + (size_t)n * 64;
  #pragma unroll
  for (int g = 0; g < 8; ++g) {
    int4 v;
    v.x = (int)(f2bf(acc[g * 2][0]) | (f2bf(acc[g * 2][1]) << 16));
    v.y = (int)(f2bf(acc[g * 2][2]) | (f2bf(acc[g * 2][3]) << 16));
    v.z = (int)(f2bf(acc[g * 2 + 1][0]) | (f2bf(acc[g * 2 + 1][1]) << 16));
    v.w = (int)(f2bf(acc[g * 2 + 1][2]) | (f2bf(acc[g * 2 + 1][3]) << 16));
    *(int4*)(out + g * 8) = v;
  }
}

// =====================================================================
// CHAMPION (round-5/round-11): BM=256 x BN=128, BK=32, 512 thr / 8
// waves (4x2), 2 blocks/CU, depth-2 dbuf, one __syncthreads per substep.
// Swizzle for 64B row stride: chunk ^= (row>>1)&3 (2-way = free),
// applied both-sides (pre-swizzled global source + swizzled ds_read).
// =====================================================================
template <int CIN, bool OUTF32, bool RELU, bool SHADOW>
__global__ __launch_bounds__(512, 4) void sconv_pipe2_kernel(
    const uint16_t* __restrict__ fin, const int* __restrict__ kmap,
    const uint16_t* __restrict__ Wt, const float* __restrict__ bias,
    float* __restrict__ outf, uint16_t* __restrict__ outb,
    const uint16_t* __restrict__ zp, int Nout) {
  constexpr int QH = CIN / 32;   // 32-col quarters per row
  constexpr int S = 27 * QH;
  __shared__ __align__(16) uint16_t As[2][256 * 32];
  __shared__ __align__(16) uint16_t Bs[2][128 * 32];
  __shared__ int idxs[27 * 256];

  const int t = threadIdx.x;
  const int lane = t & 63, w = t >> 6;
  const int wr = w >> 1, wc = w & 1;

  // bijective XCD-chunked swizzle (m204)
  const int nwg = gridDim.x;
  int bid = blockIdx.x;
  if (nwg >= 8) {
    const int q = nwg >> 3, r = nwg & 7;
    const int xcd = bid & 7, pos = bid >> 3;
    bid = (xcd < r ? xcd * (q + 1) : r * (q + 1) + (xcd - r) * q) + pos;
  }
  const int n0 = bid * 256;

  for (int i = t; i < 27 * 256; i += 512) {
    int n = n0 + (i & 255);
    idxs[i] = (n < Nout) ? kmap[(size_t)(i >> 8) * Nout + n] : -1;
  }
  __syncthreads();

  f32x4 acc[4][4] = {};

  auto stage = [&](int ss, int nb) {
    const int k = ss / QH;
    const int q = ss & (QH - 1);
    // A: 256 rows x 32 cols bf16 = 1024 x 16B chunks; 2 per thread.
    #pragma unroll
    for (int j = 0; j < 2; ++j) {
      const int base = w * 64 + j * 512;
      const int row = (base >> 2) + (lane >> 2);
      const int sw = (lane & 3) ^ ((row >> 1) & 3);
      const int idx = idxs[k * 256 + row];
      const void* srcA = (idx >= 0)
          ? (const void*)(fin + (size_t)idx * CIN + q * 32 + sw * 8)
          : (const void*)zp;
      gld_lds16(srcA, (char*)&As[nb][0] + base * 16);
    }
    // B: 128 rows x 32 cols = 512 chunks; 1 per thread
    {
      const uint16_t* wk = Wt + (size_t)k * 128 * CIN + q * 32;
      const int row = t >> 2;
      const int sw = (t & 3) ^ ((row >> 1) & 3);
      gld_lds16((const void*)(wk + (size_t)row * CIN + sw * 8),
                (char*)&Bs[nb][0] + (w * 64) * 16);
    }
  };

  stage(0, 0);
  __syncthreads();

  int cur = 0;
  for (int s = 0; s < S; ++s) {
    if (s + 1 < S) stage(s + 1, cur ^ 1);
    const char* Ab = (const char*)&As[cur][0];
    const char* Bb = (const char*)&Bs[cur][0];
    bf16x8 a[4], b[4];
    const int cl = lane >> 4;
    #pragma unroll
    for (int m = 0; m < 4; ++m) {
      int row = wr * 64 + m * 16 + (lane & 15);
      a[m] = *(const bf16x8*)(Ab + row * 64 + ((cl ^ ((row >> 1) & 3)) * 16));
    }
    #pragma unroll
    for (int n = 0; n < 4; ++n) {
      int row = wc * 64 + n * 16 + (lane & 15);
      b[n] = *(const bf16x8*)(Bb + row * 64 + ((cl ^ ((row >> 1) & 3)) * 16));
    }
    #pragma unroll
    for (int m = 0; m < 4; ++m)
      #pragma unroll
      for (int n = 0; n < 4; ++n)
        acc[m][n] = __builtin_amdgcn_mfma_f32_16x16x32_bf16(a[m], b[n], acc[m][n], 0, 0, 0);
    __syncthreads();
    cur ^= 1;
  }

  // epilogue: C/D frag: col = lane&15, row = (lane>>4)*4 + reg
  #pragma unroll
  for (int m = 0; m < 4; ++m) {
    int rbase = n0 + wr * 64 + m * 16 + ((lane >> 4) << 2);
    #pragma unroll
    for (int r = 0; r < 4; ++r) {
      int gr = rbase + r;
      if (gr < Nout) {
        #pragma unroll
        for (int n = 0; n < 4; ++n) {
          int col = wc * 64 + n * 16 + (lane & 15);
          float v = acc[m][n][r] + bias[col];
          if (RELU) v = fmaxf(v, 0.f);
          if (OUTF32) outf[(size_t)gr * 128 + col] = v;
          if (SHADOW) outb[(size_t)gr * 128 + col] = (uint16_t)f2bf(v);
        }
      }
    }
  }
}

// =====================================================================
// FALLBACK (round-1 proven path): reg-staged serial sconv
// =====================================================================
template <int CIN, bool IN_F32, bool RELU, bool WF32>
__global__ __launch_bounds__(256) void sconv_mfma_kernel(
    const void* __restrict__ fin, const int* __restrict__ kmap,
    const uint16_t* __restrict__ Wt, const float* __restrict__ bias,
    void* __restrict__ outp, int Nout) {
  constexpr int ROWB = CIN * 2;
  constexpr int CHR  = CIN / 8;
  constexpr int CPT  = (128 * CHR) / 256;
  __shared__ __align__(16) uint16_t As[128 * CIN];
  __shared__ __align__(16) uint16_t Bs[128 * CIN];
  const int t = threadIdx.x;
  const int lane = t & 63, w = t >> 6;
  const int wr = w >> 1, wc = w & 1;
  const int n0 = blockIdx.x * 128;
  f32x4 acc[4][4] = {};
  for (int k = 0; k < 27; ++k) {
    const int* __restrict__ km = kmap + (size_t)k * Nout;
    #pragma unroll
    for (int j = 0; j < CPT; ++j) {
      int c = t + j * 256;
      int row = c / CHR, c16 = c - row * CHR;
      int n = n0 + row;
      int idx = (n < Nout) ? km[n] : -1;
      int4 v = {0, 0, 0, 0};
      if (idx >= 0) {
        if (IN_F32) {
          const float* src = (const float*)fin + (size_t)idx * CIN + c16 * 8;
          float4 lo = *(const float4*)src;
          float4 hi = *(const float4*)(src + 4);
          v.x = (int)(f2bf(lo.x) | (f2bf(lo.y) << 16));
          v.y = (int)(f2bf(lo.z) | (f2bf(lo.w) << 16));
          v.z = (int)(f2bf(hi.x) | (f2bf(hi.y) << 16));
          v.w = (int)(f2bf(hi.z) | (f2bf(hi.w) << 16));
        } else {
          v = *(const int4*)((const uint16_t*)fin + (size_t)idx * CIN + c16 * 8);
        }
      }
      *(int4*)((char*)As + row * ROWB + ((c16 * 16) ^ ((row & 7) << 4))) = v;
    }
    const uint16_t* __restrict__ wkp = Wt + (size_t)k * 128 * CIN;
    #pragma unroll
    for (int j = 0; j < CPT; ++j) {
      int c = t + j * 256;
      int row = c / CHR, c16 = c - row * CHR;
      int4 v = *(const int4*)(wkp + row * CIN + c16 * 8);
      *(int4*)((char*)Bs + row * ROWB + ((c16 * 16) ^ ((row & 7) << 4))) = v;
    }
    __syncthreads();
    #pragma unroll
    for (int kk = 0; kk < CIN / 32; ++kk) {
      const int kb = (kk * 32 + ((lane >> 4) * 8)) * 2;
      bf16x8 a[4], b[4];
      #pragma unroll
      for (int m = 0; m < 4; ++m) {
        int row = wr * 64 + m * 16 + (lane & 15);
        a[m] = *(const bf16x8*)((const char*)As + row * ROWB + (kb ^ ((row & 7) << 4)));
      }
      #pragma unroll
      for (int n = 0; n < 4; ++n) {
        int row = wc * 64 + n * 16 + (lane & 15);
        b[n] = *(const bf16x8*)((const char*)Bs + row * ROWB + (kb ^ ((row & 7) << 4)));
      }
      #pragma unroll
      for (int m = 0; m < 4; ++m)
        #pragma unroll
        for (int n = 0; n < 4; ++n)
          acc[m][n] = __builtin_amdgcn_mfma_f32_16x16x32_bf16(a[m], b[n], acc[m][n], 0, 0, 0);
    }
    __syncthreads();
  }
  #pragma unroll
  for (int m = 0; m < 4; ++m) {
    int rbase = n0 + wr * 64 + m * 16 + ((lane >> 4) << 2);
    #pragma unroll
    for (int r = 0; r < 4; ++r) {
      int gr = rbase + r;
      if (gr < Nout) {
        #pragma unroll
        for (int n = 0; n < 4; ++n) {
          int col = wc * 64 + n * 16 + (lane & 15);
          float v = acc[m][n][r] + bias[col];
          if (RELU) v = fmaxf(v, 0.f);
          if (WF32) ((float*)outp)[(size_t)gr * 128 + col] = v;
          else      ((uint16_t*)outp)[(size_t)gr * 128 + col] = (uint16_t)f2bf(v);
        }
      }
    }
  }
}

extern "C" void kernel_launch(void* const* d_in, const int* in_sizes, int n_in,
                              void* d_out, int out_size, void* d_ws, size_t ws_size,
                              hipStream_t stream) {
  const float* x    = (const float*)d_in[0];
  const int*   km0  = (const int*)d_in[1];
  const int*   kmd0 = (const int*)d_in[2];
  const int*   km1  = (const int*)d_in[3];
  const int*   kmd1 = (const int*)d_in[4];
  const int*   km2  = (const int*)d_in[5];
  const int*   kmd2 = (const int*)d_in[6];
  const float* W0   = (const float*)d_in[7];
  const float* b0   = (const float*)d_in[8];
  const float* Wd0  = (const float*)d_in[9];
  const float* bd0  = (const float*)d_in[10];
  const float* W1   = (const float*)d_in[11];
  const float* b1   = (const float*)d_in[12];
  const float* Wd1  = (const float*)d_in[13];
  const float* bd1  = (const float*)d_in[14];
  const float* W2   = (const float*)d_in[15];
  const float* b2   = (const float*)d_in[16];
  const float* Wd2  = (const float*)d_in[17];
  const float* bd2  = (const float*)d_in[18];

  const int N0 = in_sizes[1] / 27;
  const int N1 = in_sizes[2] / 27;
  const int N2 = in_sizes[4] / 27;
  const int N3 = in_sizes[6] / 27;

  float* out2 = (float*)d_out;
  float* out1 = out2 + (size_t)N3 * 128;
  float* out0 = out1 + (size_t)N2 * 128;

  const size_t wsz_d0 = (size_t)27 * 64 * 128 * 2;
  const size_t wsz    = (size_t)27 * 128 * 128 * 2;
  const size_t bufA_b = 2 * ((size_t)N0 * 64 > (size_t)N1 * 128 ? (size_t)N0 * 64 : (size_t)N1 * 128);
  const size_t bufB_b = 2 * (size_t)((N1 > N2 ? N1 : N2)) * 128;

  char* p = (char*)d_ws;
  uint16_t* zp    = (uint16_t*)p; p += 512;
  uint16_t* Wt_d0 = (uint16_t*)p; p += wsz_d0;
  uint16_t* Wt_1  = (uint16_t*)p; p += wsz;
  uint16_t* Wt_d1 = (uint16_t*)p; p += wsz;
  uint16_t* Wt_2  = (uint16_t*)p; p += wsz;
  uint16_t* Wt_d2 = (uint16_t*)p; p += wsz;
  uint16_t* bufA  = (uint16_t*)p; p += bufA_b;
  uint16_t* bufB  = (uint16_t*)p;

  const size_t needed_new = 512 + wsz_d0 + 4 * wsz + bufA_b + bufB_b;

  // fused weight prep (all 5 transposes + zp zeroing), one launch
  {
    const int total = 27 * 128 * (64 + 4 * 128);
    wprep_all_kernel<<<dim3((total + 255) / 256), dim3(256), 0, stream>>>(
        Wd0, W1, Wd1, W2, Wd2, Wt_d0, Wt_1, Wt_d1, Wt_2, Wt_d2, zp);
  }

  if (ws_size >= needed_new) {
    // conv0: x -> h0 bf16 (bufA)
    conv0_kernel<<<dim3((N0 + 255) / 256), dim3(256), 0, stream>>>(x, km0, W0, b0, bufA, N0);
    // down0: h0(bufA) -> out0 f32 + bf16 shadow (bufB), relu
    sconv_pipe2_kernel<64, true, true, true>
        <<<dim3((N1 + 255) / 256), dim3(512), 0, stream>>>(bufA, kmd0, Wt_d0, bd0, out0, bufB, zp, N1);
    // conv1: out0b(bufB) -> h1 bf16 (bufA)
    sconv_pipe2_kernel<128, false, false, true>
        <<<dim3((N1 + 255) / 256), dim3(512), 0, stream>>>(bufB, km1, Wt_1, b1, nullptr, bufA, zp, N1);
    // down1: h1(bufA) -> out1 f32 + bf16 shadow (bufB), relu
    sconv_pipe2_kernel<128, true, true, true>
        <<<dim3((N2 + 255) / 256), dim3(512), 0, stream>>>(bufA, kmd1, Wt_d1, bd1, out1, bufB, zp, N2);
    // conv2: out1b(bufB) -> h2 bf16 (bufA)
    sconv_pipe2_kernel<128, false, false, true>
        <<<dim3((N2 + 255) / 256), dim3(512), 0, stream>>>(bufB, km2, Wt_2, b2, nullptr, bufA, zp, N2);
    // down2: h2(bufA) -> out2 f32 (no relu)
    sconv_pipe2_kernel<128, true, false, false>
        <<<dim3((N3 + 255) / 256), dim3(512), 0, stream>>>(bufA, kmd2, Wt_d2, bd2, out2, nullptr, zp, N3);
  } else {
    uint16_t* hbuf = (uint16_t*)((char*)d_ws + 512 + wsz_d0 + 4 * wsz);
    conv0_kernel<<<dim3((N0 + 255) / 256), dim3(256), 0, stream>>>(x, km0, W0, b0, hbuf, N0);
    sconv_mfma_kernel<64, false, true, true>
        <<<dim3((N1 + 127) / 128), dim3(256), 0, stream>>>(hbuf, kmd0, Wt_d0, bd0, out0, N1);
    sconv_mfma_kernel<128, true, false, false>
        <<<dim3((N1 + 127) / 128), dim3(256), 0, stream>>>(out0, km1, Wt_1, b1, hbuf, N1);
    sconv_mfma_kernel<128, false, true, true>
        <<<dim3((N2 + 127) / 128), dim3(256), 0, stream>>>(hbuf, kmd1, Wt_d1, bd1, out1, N2);
    sconv_mfma_kernel<128, true, false, false>
        <<<dim3((N2 + 127) / 128), dim3(256), 0, stream>>>(out1, km2, Wt_2, b2, hbuf, N2);
    sconv_mfma_kernel<128, false, false, true>
        <<<dim3((N3 + 127) / 128), dim3(256), 0, stream>>>(hbuf, kmd2, Wt_d2, bd2, out2, N3);
  }
}